// Round 6
// baseline (620.121 us; speedup 1.0000x reference)
//
#include <hip/hip_runtime.h>
#include <math.h>

#define B_   128
#define L_   32
#define T_   31
#define V_   10000
#define IC_  2048
#define WD_  512
#define H_   512
#define D_   2560
#define G3_  1536   // 3*H
#define NPAD_ 10112 // V padded to 79*128
#define NPROD_ 64                 // producer blocks (solo CUs)
#define NCONS_ 158                // consumers = 79 nb-slots x 2 teams
#define NTEAM_ 2
#define NGITILE_ (31 * 12)        // embedded gi_full gemm tiles
// k_setup block-role layout (low bids start first -> latency-critical first)
#define SU_PFX0 1
#define SU_FCW0 17
#define SU_WHH0 (SU_FCW0 + 2528)
#define SU_N    (SU_WHH0 + 384)

typedef short short8 __attribute__((ext_vector_type(8)));
typedef float f32x4  __attribute__((ext_vector_type(4)));
typedef unsigned short ushort_t;
typedef unsigned long long ull_t;

__device__ __forceinline__ unsigned short f2bf(float f) {
    unsigned int u = __builtin_bit_cast(unsigned int, f);
    unsigned int r = (u + 0x7FFFu + ((u >> 16) & 1u)) >> 16;
    return (unsigned short)r;
}
__device__ __forceinline__ float bf2f(unsigned short h) {
    unsigned int u = ((unsigned int)h) << 16;
    return __builtin_bit_cast(float, u);
}
__device__ __forceinline__ f32x4 mfma16(short8 a, short8 b, f32x4 c) {
    return __builtin_amdgcn_mfma_f32_16x16x32_bf16(a, b, c, 0, 0, 0);
}

// ---- workspace layout (byte offsets) ----
#define WS_ORDER  0          // int[128]
#define WS_LEN    512        // int[128]
#define WS_TOK    1024       // int[3968] -> ends 16896
#define WS_BAR    16896      // int (legacy, zeroed)
#define WS_GIIMG  16960      // float[128*1536]          -> ends 803392
#define WS_WHH    803392     // bf16 [32][48][512] perm  -> ends 2376256
#define WS_GIFULL 2376256    // bf16 [3968*1536]         -> ends 14565952
#define WS_OUTS   14565952   // bf16 [32*128*512]        -> ends 18760256
#define WS_FCW    18760256   // bf16 [10112*512]         -> ends 29114944
// sync flags live inside the zero-padded fcw rows [10108,10112) (4096 B):
//   - zeroed every iteration by the cvt_fcw role (rows >= V_ write 0)
//   - read as B-operand only for output cols n >= V_, which are masked
//   int sync[i*8]          : per-producer flag i in [0,64), value = step+1
//   int sync[768 + k*16+ih]: half-ready replica k in [0,8) (8B-pair loadable)
//   int sync[896 + t]      : gi_done[t] counter, target 12 (t in [0,31))

// ---------------------------------------------------------------------------
template<bool F32>
__device__ __forceinline__ uint4 load_cvt(const void* src, size_t off) {
    if constexpr (!F32) {
        return *(const uint4*)((const unsigned short*)src + off);
    } else {
        const float* p = (const float*)src + off;
        const float4 x = *(const float4*)p;
        const float4 y = *(const float4*)(p + 4);
        union { unsigned short u[8]; uint4 v; } r;
        r.u[0]=f2bf(x.x); r.u[1]=f2bf(x.y); r.u[2]=f2bf(x.z); r.u[3]=f2bf(x.w);
        r.u[4]=f2bf(y.x); r.u[5]=f2bf(y.y); r.u[6]=f2bf(y.z); r.u[7]=f2bf(y.w);
        return r.v;
    }
}

// ---------------------------------------------------------------------------
// k_setup: ONE launch for all preprocessing.
//   bid 0            : prep (sort, tok table, len_i, out tail)
//   bid [1,17)       : pfx  (gi_img 12 blocks + h0 4 blocks)
//   bid [17,2545)    : fc_w -> bf16 (pads rows >= V_ with 0, zeroes sync)
//   bid [2545,2929)  : W_hh -> bf16 permuted 32x48x512
// ---------------------------------------------------------------------------
__global__ __launch_bounds__(256) void k_setup(
    const int* __restrict__ captions,
    const int* __restrict__ cap_lens,
    const float* __restrict__ fc_w,
    const float* __restrict__ W_hh,
    const float* __restrict__ image_code,
    const float* __restrict__ W_ih,
    const float* __restrict__ b_ih,
    const float* __restrict__ init_w,
    const float* __restrict__ init_b,
    ushort_t* __restrict__ fcw_bf,
    ushort_t* __restrict__ whh_bf,
    float* __restrict__ gi_img,
    ushort_t* __restrict__ outs,
    int* __restrict__ order,
    int* __restrict__ len_i,
    int* __restrict__ tok,
    int* __restrict__ bar,
    float* __restrict__ out_tail)
{
    __shared__ __align__(16) ushort_t As[128 * 32];
    __shared__ __align__(16) ushort_t Bs[128 * 32];
    __shared__ int s_len[B_];
    __shared__ int s_ord[B_];
    const int bid = blockIdx.x;
    const int tid = threadIdx.x;

    if (bid >= SU_FCW0 && bid < SU_WHH0) {
        const int idx = (bid - SU_FCW0) * 256 + tid;
        const int row = idx >> 6;
        const int ch  = idx & 63;
        union { unsigned short u[8]; uint4 v; } r;
        if (row < V_) {
            const float* p = fc_w + (size_t)row * 512 + ch * 8;
            const float4 x = *(const float4*)p;
            const float4 y = *(const float4*)(p + 4);
            r.u[0]=f2bf(x.x); r.u[1]=f2bf(x.y); r.u[2]=f2bf(x.z); r.u[3]=f2bf(x.w);
            r.u[4]=f2bf(y.x); r.u[5]=f2bf(y.y); r.u[6]=f2bf(y.z); r.u[7]=f2bf(y.w);
        } else {
            r.v = make_uint4(0, 0, 0, 0);
        }
        *(uint4*)&fcw_bf[(size_t)row * 512 + ch * 8] = r.v;
        return;
    }
    if (bid >= SU_WHH0) {
        const int idx = (bid - SU_WHH0) * 256 + tid;
        const size_t o = (size_t)idx * 8;
        const int g = (int)(o / (48 * 512));
        const int rem = (int)(o % (48 * 512));
        const int j = rem >> 9;
        const int k = rem & 511;
        const int srow = (j >> 4) * 512 + g * 16 + (j & 15);
        const float* p = W_hh + (size_t)srow * 512 + k;
        const float4 x = *(const float4*)p;
        const float4 y = *(const float4*)(p + 4);
        union { unsigned short u[8]; uint4 v; } r;
        r.u[0]=f2bf(x.x); r.u[1]=f2bf(x.y); r.u[2]=f2bf(x.z); r.u[3]=f2bf(x.w);
        r.u[4]=f2bf(y.x); r.u[5]=f2bf(y.y); r.u[6]=f2bf(y.z); r.u[7]=f2bf(y.w);
        *(uint4*)&whh_bf[o] = r.v;
        return;
    }

    // prep + pfx both need the sorted order: recompute locally
    if (tid < B_) s_len[tid] = cap_lens[tid];
    __syncthreads();
    if (tid < B_) {
        const int myl = s_len[tid];
        int rank = 0;
        for (int k = 0; k < B_; ++k) {
            const int lk = s_len[k];
            if (lk > myl || (lk == myl && k < tid)) rank++;
        }
        s_ord[rank] = tid;
    }
    __syncthreads();

    if (bid == 0) {
        if (tid == 0) *bar = 0;
        if (tid < B_) {
            const int o = s_ord[tid];
            order[tid] = o;
            const int ln = s_len[o] - 1;
            len_i[tid] = ln;
            out_tail[B_ * L_ + tid]      = (float)ln;
            out_tail[B_ * L_ + B_ + tid] = (float)o;
        }
        __syncthreads();
        for (int i = tid; i < B_ * L_; i += 256) {
            const int b = i / L_, l = i % L_;
            const int c = captions[s_ord[b] * L_ + l];
            out_tail[i] = (float)c;
            if (l < T_) tok[l * B_ + b] = c;
        }
        return;
    }

    // ---- pfx: gi_img (bids 1..12) / h0 (bids 13..16) ----
    const int px = bid - SU_PFX0;
    const bool isH0 = px >= 12;
    const float* Bm = isH0 ? init_w : W_ih;
    const int ldb = isH0 ? IC_ : D_;
    const int n0 = isH0 ? (px - 12) * 128 : px * 128;
    const float* bias = isH0 ? init_b : b_ih;

    const int w = tid >> 6, lane = tid & 63, quad = lane >> 4, lr = lane & 15;
    const int srow = tid >> 2, ch = tid & 3;
    const int wm = (w & 1) * 64, wn = (w >> 1) * 64;

    const int ar0 = s_ord[srow];
    const int ar1 = s_ord[srow + 64];
    const int br0 = n0 + srow, br1 = n0 + srow + 64;

    f32x4 acc[4][4];
    const f32x4 z4 = {0.f, 0.f, 0.f, 0.f};
#pragma unroll
    for (int i = 0; i < 4; ++i)
#pragma unroll
        for (int j = 0; j < 4; ++j) acc[i][j] = z4;

    uint4 a0 = load_cvt<true>(image_code, (size_t)ar0 * IC_ + ch * 8);
    uint4 a1 = load_cvt<true>(image_code, (size_t)ar1 * IC_ + ch * 8);
    uint4 b0 = load_cvt<true>(Bm, (size_t)br0 * ldb + ch * 8);
    uint4 b1 = load_cvt<true>(Bm, (size_t)br1 * ldb + ch * 8);

    for (int k0 = 0; k0 < IC_; k0 += 32) {
        __syncthreads();
        *(uint4*)&As[(srow)      * 32 + ch * 8] = a0;
        *(uint4*)&As[(srow + 64) * 32 + ch * 8] = a1;
        *(uint4*)&Bs[(srow)      * 32 + ch * 8] = b0;
        *(uint4*)&Bs[(srow + 64) * 32 + ch * 8] = b1;
        __syncthreads();
        short8 af[4], bfr[4];
#pragma unroll
        for (int i = 0; i < 4; ++i) af[i]  = *(const short8*)&As[(wm + i * 16 + lr) * 32 + quad * 8];
#pragma unroll
        for (int j = 0; j < 4; ++j) bfr[j] = *(const short8*)&Bs[(wn + j * 16 + lr) * 32 + quad * 8];
        if (k0 + 32 < IC_) {
            a0 = load_cvt<true>(image_code, (size_t)ar0 * IC_ + k0 + 32 + ch * 8);
            a1 = load_cvt<true>(image_code, (size_t)ar1 * IC_ + k0 + 32 + ch * 8);
            b0 = load_cvt<true>(Bm, (size_t)br0 * ldb + k0 + 32 + ch * 8);
            b1 = load_cvt<true>(Bm, (size_t)br1 * ldb + k0 + 32 + ch * 8);
        }
#pragma unroll
        for (int i = 0; i < 4; ++i)
#pragma unroll
            for (int j = 0; j < 4; ++j) acc[i][j] = mfma16(af[i], bfr[j], acc[i][j]);
    }

#pragma unroll
    for (int i = 0; i < 4; ++i)
#pragma unroll
        for (int r = 0; r < 4; ++r) {
            const int m = wm + i * 16 + quad * 4 + r;
#pragma unroll
            for (int j = 0; j < 4; ++j) {
                const int n = n0 + wn + j * 16 + lr;
                const float v = acc[i][j][r] + bias[n];
                if (isH0) outs[(size_t)m * H_ + n] = f2bf(v);
                else      gi_img[(size_t)m * G3_ + n] = v;
            }
        }
}

// ---------------------------------------------------------------------------
// Embedded gi_full tile worker (verbatim gemm128 accumulation -> bit-identical
// values). tile = t*12 + nt; computes gi_full[t*128 .. +128)[nt*128 .. +128).
// Epilogue: + gi_img[b] (+ b_hh for r,z), f2bf, PAIRED 4B ATOMIC stores
// (write-through to coherence), then vmcnt(0) + barrier + gi_done[t] += 1.
// ---------------------------------------------------------------------------
__device__ __forceinline__ void gi_tile_worker(
    int tile, ushort_t* sm,
    const float* __restrict__ embed_w, const int* __restrict__ tok,
    const float* __restrict__ W_ih_tail, const float* __restrict__ gi_img,
    const float* __restrict__ b_hh, ushort_t* __restrict__ gi_full,
    int* __restrict__ gidone, int tid)
{
    const int t = tile / 12, nt = tile - t * 12;
    const int m0 = t * 128, n0 = nt * 128;
    ushort_t* As = sm;
    ushort_t* Bs = sm + 4096;
    const int w = tid >> 6, lane = tid & 63, quad = lane >> 4, lr = lane & 15;
    const int srow = tid >> 2, ch = tid & 3;
    const int wm = (w & 1) * 64, wn = (w >> 1) * 64;

    const int ar0 = tok[m0 + srow];
    const int ar1 = tok[m0 + srow + 64];
    const int br0 = n0 + srow, br1 = n0 + srow + 64;

    f32x4 acc[4][4];
    const f32x4 z4 = {0.f, 0.f, 0.f, 0.f};
#pragma unroll
    for (int i = 0; i < 4; ++i)
#pragma unroll
        for (int j = 0; j < 4; ++j) acc[i][j] = z4;

    uint4 a0 = load_cvt<true>(embed_w, (size_t)ar0 * WD_ + ch * 8);
    uint4 a1 = load_cvt<true>(embed_w, (size_t)ar1 * WD_ + ch * 8);
    uint4 b0 = load_cvt<true>(W_ih_tail, (size_t)br0 * D_ + ch * 8);
    uint4 b1 = load_cvt<true>(W_ih_tail, (size_t)br1 * D_ + ch * 8);

    for (int k0 = 0; k0 < WD_; k0 += 32) {
        __syncthreads();
        *(uint4*)&As[(srow)      * 32 + ch * 8] = a0;
        *(uint4*)&As[(srow + 64) * 32 + ch * 8] = a1;
        *(uint4*)&Bs[(srow)      * 32 + ch * 8] = b0;
        *(uint4*)&Bs[(srow + 64) * 32 + ch * 8] = b1;
        __syncthreads();
        short8 af[4], bfr[4];
#pragma unroll
        for (int i = 0; i < 4; ++i) af[i]  = *(const short8*)&As[(wm + i * 16 + lr) * 32 + quad * 8];
#pragma unroll
        for (int j = 0; j < 4; ++j) bfr[j] = *(const short8*)&Bs[(wn + j * 16 + lr) * 32 + quad * 8];
        if (k0 + 32 < WD_) {
            a0 = load_cvt<true>(embed_w, (size_t)ar0 * WD_ + k0 + 32 + ch * 8);
            a1 = load_cvt<true>(embed_w, (size_t)ar1 * WD_ + k0 + 32 + ch * 8);
            b0 = load_cvt<true>(W_ih_tail, (size_t)br0 * D_ + k0 + 32 + ch * 8);
            b1 = load_cvt<true>(W_ih_tail, (size_t)br1 * D_ + k0 + 32 + ch * 8);
        }
#pragma unroll
        for (int i = 0; i < 4; ++i)
#pragma unroll
            for (int j = 0; j < 4; ++j) acc[i][j] = mfma16(af[i], bfr[j], acc[i][j]);
    }

#pragma unroll
    for (int i = 0; i < 4; ++i)
#pragma unroll
        for (int r = 0; r < 4; ++r) {
            const int m = m0 + wm + i * 16 + quad * 4 + r;
#pragma unroll
            for (int j = 0; j < 4; ++j) {
                const int n = n0 + wn + j * 16 + lr;
                const float extra = (n < 1024) ? b_hh[n] : 0.f;
                const float v = acc[i][j][r] + gi_img[(size_t)(m & 127) * G3_ + n] + extra;
                const unsigned int hb = (unsigned int)f2bf(v);
                const unsigned int pv = (unsigned int)__shfl_xor((int)hb, 1);
                if ((lr & 1) == 0) {
                    const unsigned int word = hb | (pv << 16);
                    __hip_atomic_store((unsigned int*)&gi_full[(size_t)m * G3_ + n], word,
                                       __ATOMIC_RELAXED, __HIP_MEMORY_SCOPE_AGENT);
                }
            }
        }
    asm volatile("s_waitcnt vmcnt(0)" ::: "memory");
    __syncthreads();
    if (tid == 0)
        __hip_atomic_fetch_add(&gidone[t], 1, __ATOMIC_RELAXED, __HIP_MEMORY_SCOPE_AGENT);
}

// ---------------------------------------------------------------------------
// FUSED gi-gemm + recurrence + output projection (R6).
// 86 KB LDS -> 1 block/CU; grid 222 <= 256 CUs, all resident, no ordering
// assumption. gi_full gemm EMBEDDED as a work pool: producers do tiles
// [0,64) (steps 0-5, one each), consumers do [64,372) strided; gi_done[t]
// counters (12 per step) gate producer gi loads. Deadlock-free: gi work is
// unconditional; producers wait only on producer flags + gi counters;
// consumers wait only on half-ready.
// Producers [0,64): per step -- gi load (top of loop, hidden under h+MFMA),
//   h direct-to-reg, 48 MFMA, gates, write-through store, flags, wave-0 poll
//   (flags AND gi_done[step+1]).
// Consumers [64,222): nb-affine (nb=cid%79, team=cid/79); preds GEMM BK=64,
//   LDS stride 72 (16B-aligned, 2-way-free banks), reg double-buffer ->
//   8 rounds of 32 MFMA instead of 16 rounds of 16.
// ---------------------------------------------------------------------------
#define PBS_STR 520
#define CAS_STR 72
__global__ __launch_bounds__(256, 1) void k_fused(
    const ushort_t* __restrict__ whh_bf,   // (32,48,512)
    ushort_t* __restrict__ gi_full,        // (31*128,1536) -- written here now
    const float* __restrict__ b_hh,        // (1536)
    ushort_t* __restrict__ outs,           // (32,128,512)
    const ushort_t* __restrict__ fcw_bf,   // (10112,512)
    const float* __restrict__ fc_b,        // (10000)
    const int* __restrict__ len_i,         // (128)
    float* __restrict__ out,               // (128,31,10000)
    int* __restrict__ sync,                // flags + replicas + gi_done
    const float* __restrict__ embed_w,     // (V, 512)
    const int* __restrict__ tok,           // (31*128)
    const float* __restrict__ W_ih_tail,   // W_ih + IC_ (1536 x 2560 rows)
    const float* __restrict__ gi_img)      // (128,1536) f32
{
    __shared__ __align__(16) ushort_t sm[43008];   // 86,016 B -> 1 block/CU
    const int bid = blockIdx.x;
    const int tid = threadIdx.x;
    const int w = tid >> 6, lane = tid & 63, quad = lane >> 4, lr = lane & 15;
    int* gidone = &sync[896];

    if (bid < NPROD_) {
        // ---------------- producer (solo CU) ----------------
        // prelude: one gi tile (tiles 0..63 cover steps 0..5)
        gi_tile_worker(bid, sm, embed_w, tok, W_ih_tail, gi_img, b_hh,
                       gi_full, gidone, tid);

        __builtin_amdgcn_s_setprio(1);
        const int g = bid & 31;
        const int ih = bid >> 5;
        const bool leader = (bid == (ih << 5));   // bid 0 and 32
        ushort_t* Bs = sm;                 // 48 x 520 (reuse after worker)

        __syncthreads();                   // worker LDS reads done (it barriers)
        const ushort_t* wsrc = whh_bf + (size_t)g * 48 * 512;
        for (int i = tid; i < 48 * 64; i += 256) {
            const int row = i >> 6, c = i & 63;
            *(uint4*)&Bs[row * PBS_STR + c * 8] = *(const uint4*)&wsrc[row * 512 + c * 8];
        }
        const int cg = g * 16 + lr;        // gh col
        const float bhn = b_hh[1024 + cg];
        __syncthreads();

        // gate: gi step 0 must be complete (tiles 0..11, done by producers 0-11)
        if (tid == 0) {
            while (__hip_atomic_load(&gidone[0], __ATOMIC_RELAXED, __HIP_MEMORY_SCOPE_AGENT) < 12)
                __builtin_amdgcn_s_sleep(4);
        }
        __syncthreads();

        // h_old carried in registers (bf16-rounded); memory load only for h0
        float hold_reg[4];
        {
            const ushort_t* h0p = outs + (size_t)ih * 64 * 512;
#pragma unroll
            for (int r = 0; r < 4; ++r)
                hold_reg[r] = bf2f(h0p[(size_t)(w * 16 + quad * 4 + r) * 512 + cg]);
        }

        for (int step = 0; step < T_; ++step) {
            const ushort_t* hsrc = outs + (size_t)step * (128 * 512) + (size_t)ih * 64 * 512;

            // gi loads for THIS step (gated by previous poll / prologue);
            // issued first, consumed after MFMA -> latency hidden
            ushort_t gi0[4], gi1[4], gi2[4];
            {
                const size_t gb = (size_t)step * 128 * G3_;
#pragma unroll
                for (int r = 0; r < 4; ++r) {
                    const int b = ih * 64 + w * 16 + quad * 4 + r;
                    const ushort_t* p = gi_full + gb + (size_t)b * G3_ + cg;
                    gi0[r] = p[0]; gi1[r] = p[512]; gi2[r] = p[1024];
                }
            }

            // h_t A-fragments: per-lane contiguous 16B chunks straight to regs
            uint4 hv[16];
            const ushort_t* hrow = hsrc + (size_t)(w * 16 + lr) * 512 + quad * 8;
#pragma unroll
            for (int kk = 0; kk < 16; ++kk)
                hv[kk] = *(const uint4*)(hrow + kk * 32);

            f32x4 acc[3];
#pragma unroll
            for (int j = 0; j < 3; ++j) acc[j] = (f32x4){0.f, 0.f, 0.f, 0.f};
#pragma unroll
            for (int kk = 0; kk < 16; ++kk) {
                union { uint4 v; short8 s; } cc; cc.v = hv[kk];
                const short8 af = cc.s;
#pragma unroll
                for (int j = 0; j < 3; ++j) {
                    const short8 bf = *(const short8*)&Bs[(j * 16 + lr) * PBS_STR + kk * 32 + quad * 8];
                    acc[j] = mfma16(af, bf, acc[j]);
                }
            }

            // gates (C-layout: col=lr, row=quad*4+r)
            ushort_t* hdst = outs + (size_t)(step + 1) * (128 * 512);
#pragma unroll
            for (int r = 0; r < 4; ++r) {
                const int b = ih * 64 + w * 16 + quad * 4 + r;
                const float ir  = bf2f(gi0[r]);
                const float iz  = bf2f(gi1[r]);
                const float in_ = bf2f(gi2[r]);
                const float hr = acc[0][r];
                const float hz = acc[1][r];
                const float hn = acc[2][r] + bhn;
                const float rg = 1.f / (1.f + __expf(-(ir + hr)));
                const float zg = 1.f / (1.f + __expf(-(iz + hz)));
                const float nn = tanhf(in_ + rg * hn);
                const float hnew = (1.f - zg) * nn + zg * hold_reg[r];
                const unsigned int hb = (unsigned int)f2bf(hnew);
                hold_reg[r] = bf2f((unsigned short)hb);   // bit-compat carry
                const unsigned int pv = (unsigned int)__shfl_xor((int)hb, 1);
                if ((lr & 1) == 0) {
                    const unsigned int word = hb | (pv << 16);
                    __hip_atomic_store((unsigned int*)&hdst[(size_t)b * 512 + cg], word,
                                       __ATOMIC_RELAXED, __HIP_MEMORY_SCOPE_AGENT);
                }
            }

            // release: drain write-through stores, then distributed signal
            asm volatile("s_waitcnt vmcnt(0)" ::: "memory");
            __syncthreads();
            const int tgt = step + 1;
            if (tid == 0)
                __hip_atomic_store(&sync[bid * 8], tgt,
                                   __ATOMIC_RELAXED, __HIP_MEMORY_SCOPE_AGENT);

            // wave 0 polls: 32 same-half flags AND gi_done[step+1]
            if (w == 0 && (step < T_ - 1 || leader)) {
                const int* pf = &sync[(ih * 32 + (lane & 31)) * 8];
                const bool needgi = (step + 1 < T_);
                for (;;) {
                    const int v = __hip_atomic_load(pf, __ATOMIC_RELAXED, __HIP_MEMORY_SCOPE_AGENT);
                    const int gd = (needgi && lane == 0)
                        ? __hip_atomic_load(&gidone[step + 1], __ATOMIC_RELAXED, __HIP_MEMORY_SCOPE_AGENT)
                        : 12;
                    if (__all(v >= tgt) && __all(gd >= 12)) break;
                    __builtin_amdgcn_s_sleep(1);
                }
                if (leader && lane == 0) {
#pragma unroll
                    for (int k = 0; k < 8; ++k)
                        __hip_atomic_store(&sync[768 + k * 16 + ih], tgt,
                                           __ATOMIC_RELAXED, __HIP_MEMORY_SCOPE_AGENT);
                }
            }
            __syncthreads();          // release waves 1-3
            asm volatile("" ::: "memory");
        }
    } else {
        // ---------------- nb-affine consumer (solo CU) ----------------
        const int cid = bid - NPROD_;          // [0, 158)

        // prelude: gi tiles [64, 372) strided by NCONS_ (<= 2 each)
        for (int tix = NPROD_ + cid; tix < NGITILE_; tix += NCONS_)
            gi_tile_worker(tix, sm, embed_w, tok, W_ih_tail, gi_img, b_hh,
                           gi_full, gidone, tid);
        __syncthreads();

        const int nb = cid % 79;               // FIXED fcw slab per block
        const int team = cid / 79;             // {0, 1}
        const int n0 = nb * 128;
        ushort_t* As = sm;                     // 128 x 72 (stride-padded)
        ushort_t* Bs = sm + 128 * CAS_STR;
        const int srow = tid >> 3, ch8 = (tid & 7) * 8;   // BK=64 staging coords
        const int wm = (w & 1) * 64, wn = (w >> 1) * 64;
        const ull_t* hready = (const ull_t*)&sync[768 + (cid & 7) * 16];

        float fcb[4];
#pragma unroll
        for (int j = 0; j < 4; ++j) {
            const int n = n0 + wn + j * 16 + lr;
            fcb[j] = (n < V_) ? fc_b[n] : 0.f;
        }

        for (int t = team; t < T_; t += NTEAM_) {
            if (tid == 0) {
                for (;;) {
                    const ull_t hv8 = __hip_atomic_load(hready, __ATOMIC_RELAXED, __HIP_MEMORY_SCOPE_AGENT);
                    const int l0 = (int)(unsigned int)(hv8 & 0xffffffffull);
                    const int l1 = (int)(unsigned int)(hv8 >> 32);
                    if (l0 > t && l1 > t) break;
                    __builtin_amdgcn_s_sleep(16);
                }
            }
            __syncthreads();

            const ushort_t* A = outs + (size_t)(t + 1) * (128 * 512);

            f32x4 acc[4][4];
            const f32x4 z4 = {0.f, 0.f, 0.f, 0.f};
#pragma unroll
            for (int i = 0; i < 4; ++i)
#pragma unroll
                for (int j = 0; j < 4; ++j) acc[i][j] = z4;

            uint4 av[4], bv[4];
#pragma unroll
            for (int p = 0; p < 4; ++p) {
                av[p] = *(const uint4*)&A[(size_t)(srow + 32 * p) * 512 + ch8];
                bv[p] = *(const uint4*)&fcw_bf[(size_t)(n0 + srow + 32 * p) * 512 + ch8];
            }

            for (int k0 = 0; k0 < 512; k0 += 64) {
                __syncthreads();
#pragma unroll
                for (int p = 0; p < 4; ++p) {
                    *(uint4*)&As[(srow + 32 * p) * CAS_STR + ch8] = av[p];
                    *(uint4*)&Bs[(srow + 32 * p) * CAS_STR + ch8] = bv[p];
                }
                __syncthreads();
                if (k0 + 64 < 512) {
#pragma unroll
                    for (int p = 0; p < 4; ++p) {
                        av[p] = *(const uint4*)&A[(size_t)(srow + 32 * p) * 512 + k0 + 64 + ch8];
                        bv[p] = *(const uint4*)&fcw_bf[(size_t)(n0 + srow + 32 * p) * 512 + k0 + 64 + ch8];
                    }
                }
                // kk = 0, then kk = 1 -> same accumulation order as BK=32
#pragma unroll
                for (int kk = 0; kk < 2; ++kk) {
                    short8 af[4], bfr[4];
#pragma unroll
                    for (int i = 0; i < 4; ++i)
                        af[i]  = *(const short8*)&As[(wm + i * 16 + lr) * CAS_STR + kk * 32 + quad * 8];
#pragma unroll
                    for (int j = 0; j < 4; ++j)
                        bfr[j] = *(const short8*)&Bs[(wn + j * 16 + lr) * CAS_STR + kk * 32 + quad * 8];
#pragma unroll
                    for (int i = 0; i < 4; ++i)
#pragma unroll
                        for (int j = 0; j < 4; ++j) acc[i][j] = mfma16(af[i], bfr[j], acc[i][j]);
                }
            }

#pragma unroll
            for (int i = 0; i < 4; ++i)
#pragma unroll
                for (int r = 0; r < 4; ++r) {
                    const int b = wm + i * 16 + quad * 4 + r;
                    const bool act = (t < len_i[b]);
                    const size_t base = (size_t)b * T_ * V_ + (size_t)t * V_;
#pragma unroll
                    for (int j = 0; j < 4; ++j) {
                        const int n = n0 + wn + j * 16 + lr;
                        if (n < V_) out[base + n] = act ? (acc[i][j][r] + fcb[j]) : 0.f;
                    }
                }
        }
    }
}

// ---------------------------------------------------------------------------
extern "C" void kernel_launch(void* const* d_in, const int* in_sizes, int n_in,
                              void* d_out, int out_size, void* d_ws, size_t ws_size,
                              hipStream_t stream) {
    const float* image_code = (const float*)d_in[0];
    const int*   captions   = (const int*)d_in[1];
    const int*   cap_lens   = (const int*)d_in[2];
    const float* embed_w    = (const float*)d_in[3];
    const float* W_ih       = (const float*)d_in[4];
    const float* W_hh       = (const float*)d_in[5];
    const float* b_ih       = (const float*)d_in[6];
    const float* b_hh       = (const float*)d_in[7];
    const float* fc_w       = (const float*)d_in[8];
    const float* fc_b       = (const float*)d_in[9];
    const float* init_w     = (const float*)d_in[10];
    const float* init_b     = (const float*)d_in[11];

    float* out = (float*)d_out;
    char* ws = (char*)d_ws;
    int*      order   = (int*)(ws + WS_ORDER);
    int*      len_i   = (int*)(ws + WS_LEN);
    int*      tok     = (int*)(ws + WS_TOK);
    int*      bar     = (int*)(ws + WS_BAR);
    float*    gi_img  = (float*)(ws + WS_GIIMG);
    ushort_t* whh_bf  = (ushort_t*)(ws + WS_WHH);
    ushort_t* gi_full = (ushort_t*)(ws + WS_GIFULL);
    ushort_t* outs_bf = (ushort_t*)(ws + WS_OUTS);
    ushort_t* fcw_bf  = (ushort_t*)(ws + WS_FCW);
    int*      sync    = (int*)(fcw_bf + ((size_t)NPAD_ - 4) * 512);

    // 1) one setup launch: prep + pfx (gi_img, h0) + both weight converts
    hipLaunchKernelGGL(k_setup, dim3(SU_N), dim3(256), 0, stream,
                       captions, cap_lens, fc_w, W_hh,
                       image_code, W_ih, b_ih, init_w, init_b,
                       fcw_bf, whh_bf, gi_img, outs_bf,
                       order, len_i, tok, bar,
                       out + (size_t)B_ * T_ * V_);

    // 2) fused: embedded gi_full gemm + recurrence + output projection
    hipLaunchKernelGGL(k_fused, dim3(NPROD_ + NCONS_), dim3(256), 0, stream,
                       whh_bf, gi_full, b_hh, outs_bf,
                       fcw_bf, fc_b, len_i, out, sync,
                       embed_w, tok, W_ih + IC_, gi_img);
}

// Round 7
// 463.370 us; speedup vs baseline: 1.3383x; 1.3383x over previous
//
#include <hip/hip_runtime.h>
#include <math.h>

#define B_   128
#define L_   32
#define T_   31
#define V_   10000
#define IC_  2048
#define WD_  512
#define H_   512
#define D_   2560
#define G3_  1536   // 3*H
#define NPAD_ 10112 // V padded to 79*128
#define NPROD_ 64                 // producer blocks (solo CUs)
#define NCONS_ 158                // consumers = 79 nb-slots x 2 teams
#define NTEAM_ 2
// k_setup block-role layout
#define SU_PFX0 1
#define SU_GI0  17                // [17, 389): gi_wemb tiles (31*12)
#define SU_FCW0 389               // [389, 2917)
#define SU_WHH0 2917              // [2917, 3301)
#define SU_N    3301

typedef short short8 __attribute__((ext_vector_type(8)));
typedef float f32x4  __attribute__((ext_vector_type(4)));
typedef unsigned short ushort_t;
typedef unsigned long long ull_t;

__device__ __forceinline__ unsigned short f2bf(float f) {
    unsigned int u = __builtin_bit_cast(unsigned int, f);
    unsigned int r = (u + 0x7FFFu + ((u >> 16) & 1u)) >> 16;
    return (unsigned short)r;
}
__device__ __forceinline__ float bf2f(unsigned short h) {
    unsigned int u = ((unsigned int)h) << 16;
    return __builtin_bit_cast(float, u);
}
__device__ __forceinline__ f32x4 mfma16(short8 a, short8 b, f32x4 c) {
    return __builtin_amdgcn_mfma_f32_16x16x32_bf16(a, b, c, 0, 0, 0);
}

// ---- workspace layout (byte offsets) ----
#define WS_ORDER  0          // int[128]
#define WS_LEN    512        // int[128]
#define WS_TOK    1024       // int[3968] (unused now, kept for layout)
#define WS_BAR    16896      // int (legacy, zeroed)
#define WS_GIIMG  16960      // float[128*1536]          -> ends 803392
#define WS_WHH    803392     // bf16 [32][48][512] perm  -> ends 2376256
#define WS_GIWEMB 2376256    // bf16 [3968*1536]         -> ends 14565952
#define WS_OUTS   14565952   // bf16 [32*128*512]        -> ends 18760256
#define WS_FCW    18760256   // bf16 [10112*512]         -> ends 29114944
// sync flags live inside the zero-padded fcw rows [10108,10112) (4096 B):
//   - zeroed every iteration by the cvt_fcw role (rows >= V_ write 0)
//   - read as B-operand only for output cols n >= V_, which are masked
//   int sync[i*8]          : per-producer flag i in [0,64), value = step+1
//   int sync[768 + k*16+ih]: half-ready replica k in [0,8) (8B-pair loadable)

// ---------------------------------------------------------------------------
template<bool F32>
__device__ __forceinline__ uint4 load_cvt(const void* src, size_t off) {
    if constexpr (!F32) {
        return *(const uint4*)((const unsigned short*)src + off);
    } else {
        const float* p = (const float*)src + off;
        const float4 x = *(const float4*)p;
        const float4 y = *(const float4*)(p + 4);
        union { unsigned short u[8]; uint4 v; } r;
        r.u[0]=f2bf(x.x); r.u[1]=f2bf(x.y); r.u[2]=f2bf(x.z); r.u[3]=f2bf(x.w);
        r.u[4]=f2bf(y.x); r.u[5]=f2bf(y.y); r.u[6]=f2bf(y.z); r.u[7]=f2bf(y.w);
        return r.v;
    }
}

// ---------------------------------------------------------------------------
// k_setup: ONE launch for ALL preprocessing (no intra-kernel dependencies;
// every role that needs the sorted order recomputes it locally from cap_lens).
//   bid 0            : prep (sort, len_i, order, out tail)
//   bid [1,17)       : pfx  (gi_img 12 blocks + h0 4 blocks)
//   bid [17,389)     : gi_wemb = emb @ W_ih[:,2048:]^T  (372 tiles, PURE --
//                      no gi_img/b_hh adds; producer folds those in regs)
//   bid [389,2917)   : fc_w -> bf16 (pads rows >= V_ with 0, zeroes sync)
//   bid [2917,3301)  : W_hh -> bf16 permuted 32x48x512
// ---------------------------------------------------------------------------
__global__ __launch_bounds__(256) void k_setup(
    const int* __restrict__ captions,
    const int* __restrict__ cap_lens,
    const float* __restrict__ fc_w,
    const float* __restrict__ W_hh,
    const float* __restrict__ image_code,
    const float* __restrict__ W_ih,
    const float* __restrict__ b_ih,
    const float* __restrict__ init_w,
    const float* __restrict__ init_b,
    const float* __restrict__ embed_w,
    ushort_t* __restrict__ fcw_bf,
    ushort_t* __restrict__ whh_bf,
    float* __restrict__ gi_img,
    ushort_t* __restrict__ gi_wemb,
    ushort_t* __restrict__ outs,
    int* __restrict__ order,
    int* __restrict__ len_i,
    int* __restrict__ bar,
    float* __restrict__ out_tail)
{
    __shared__ __align__(16) ushort_t As[128 * 32];
    __shared__ __align__(16) ushort_t Bs[128 * 32];
    __shared__ int s_len[B_];
    __shared__ int s_ord[B_];
    const int bid = blockIdx.x;
    const int tid = threadIdx.x;

    if (bid >= SU_FCW0 && bid < SU_WHH0) {
        // ---- fc_w convert ----
        const int idx = (bid - SU_FCW0) * 256 + tid;
        const int row = idx >> 6;
        const int ch  = idx & 63;
        union { unsigned short u[8]; uint4 v; } r;
        if (row < V_) {
            const float* p = fc_w + (size_t)row * 512 + ch * 8;
            const float4 x = *(const float4*)p;
            const float4 y = *(const float4*)(p + 4);
            r.u[0]=f2bf(x.x); r.u[1]=f2bf(x.y); r.u[2]=f2bf(x.z); r.u[3]=f2bf(x.w);
            r.u[4]=f2bf(y.x); r.u[5]=f2bf(y.y); r.u[6]=f2bf(y.z); r.u[7]=f2bf(y.w);
        } else {
            r.v = make_uint4(0, 0, 0, 0);
        }
        *(uint4*)&fcw_bf[(size_t)row * 512 + ch * 8] = r.v;
        return;
    }
    if (bid >= SU_WHH0) {
        // ---- W_hh convert/permute ----
        const int idx = (bid - SU_WHH0) * 256 + tid;
        const size_t o = (size_t)idx * 8;
        const int g = (int)(o / (48 * 512));
        const int rem = (int)(o % (48 * 512));
        const int j = rem >> 9;
        const int k = rem & 511;
        const int srow = (j >> 4) * 512 + g * 16 + (j & 15);
        const float* p = W_hh + (size_t)srow * 512 + k;
        const float4 x = *(const float4*)p;
        const float4 y = *(const float4*)(p + 4);
        union { unsigned short u[8]; uint4 v; } r;
        r.u[0]=f2bf(x.x); r.u[1]=f2bf(x.y); r.u[2]=f2bf(x.z); r.u[3]=f2bf(x.w);
        r.u[4]=f2bf(y.x); r.u[5]=f2bf(y.y); r.u[6]=f2bf(y.z); r.u[7]=f2bf(y.w);
        *(uint4*)&whh_bf[o] = r.v;
        return;
    }

    // roles below need the sorted order: recompute locally (O(128^2), ~µs)
    if (tid < B_) s_len[tid] = cap_lens[tid];
    __syncthreads();
    if (tid < B_) {
        const int myl = s_len[tid];
        int rank = 0;
        for (int k = 0; k < B_; ++k) {
            const int lk = s_len[k];
            if (lk > myl || (lk == myl && k < tid)) rank++;
        }
        s_ord[rank] = tid;
    }
    __syncthreads();

    if (bid == 0) {
        // ---- prep ----
        if (tid == 0) *bar = 0;
        if (tid < B_) {
            const int o = s_ord[tid];
            order[tid] = o;
            const int ln = s_len[o] - 1;
            len_i[tid] = ln;
            out_tail[B_ * L_ + tid]      = (float)ln;
            out_tail[B_ * L_ + B_ + tid] = (float)o;
        }
        __syncthreads();
        for (int i = tid; i < B_ * L_; i += 256) {
            const int b = i / L_, l = i % L_;
            out_tail[i] = (float)captions[s_ord[b] * L_ + l];
        }
        return;
    }

    const int w = tid >> 6, lane = tid & 63, quad = lane >> 4, lr = lane & 15;
    const int srow = tid >> 2, ch = tid & 3;
    const int wm = (w & 1) * 64, wn = (w >> 1) * 64;

    f32x4 acc[4][4];
    const f32x4 z4 = {0.f, 0.f, 0.f, 0.f};
#pragma unroll
    for (int i = 0; i < 4; ++i)
#pragma unroll
        for (int j = 0; j < 4; ++j) acc[i][j] = z4;

    if (bid >= SU_GI0) {
        // ---- gi_wemb tile: t = ti/12, nt = ti%12, K = 512 ----
        const int ti = bid - SU_GI0;
        const int t = ti / 12, nt = ti - t * 12;
        const int n0 = nt * 128;
        const int ar0 = captions[s_ord[srow]      * L_ + t];
        const int ar1 = captions[s_ord[srow + 64] * L_ + t];
        const int br0 = n0 + srow, br1 = n0 + srow + 64;
        const float* Wt = W_ih + IC_;          // rows stride D_

        uint4 a0 = load_cvt<true>(embed_w, (size_t)ar0 * WD_ + ch * 8);
        uint4 a1 = load_cvt<true>(embed_w, (size_t)ar1 * WD_ + ch * 8);
        uint4 b0 = load_cvt<true>(Wt, (size_t)br0 * D_ + ch * 8);
        uint4 b1 = load_cvt<true>(Wt, (size_t)br1 * D_ + ch * 8);

        for (int k0 = 0; k0 < WD_; k0 += 32) {
            __syncthreads();
            *(uint4*)&As[(srow)      * 32 + ch * 8] = a0;
            *(uint4*)&As[(srow + 64) * 32 + ch * 8] = a1;
            *(uint4*)&Bs[(srow)      * 32 + ch * 8] = b0;
            *(uint4*)&Bs[(srow + 64) * 32 + ch * 8] = b1;
            __syncthreads();
            short8 af[4], bfr[4];
#pragma unroll
            for (int i = 0; i < 4; ++i) af[i]  = *(const short8*)&As[(wm + i * 16 + lr) * 32 + quad * 8];
#pragma unroll
            for (int j = 0; j < 4; ++j) bfr[j] = *(const short8*)&Bs[(wn + j * 16 + lr) * 32 + quad * 8];
            if (k0 + 32 < WD_) {
                a0 = load_cvt<true>(embed_w, (size_t)ar0 * WD_ + k0 + 32 + ch * 8);
                a1 = load_cvt<true>(embed_w, (size_t)ar1 * WD_ + k0 + 32 + ch * 8);
                b0 = load_cvt<true>(Wt, (size_t)br0 * D_ + k0 + 32 + ch * 8);
                b1 = load_cvt<true>(Wt, (size_t)br1 * D_ + k0 + 32 + ch * 8);
            }
#pragma unroll
            for (int i = 0; i < 4; ++i)
#pragma unroll
                for (int j = 0; j < 4; ++j) acc[i][j] = mfma16(af[i], bfr[j], acc[i][j]);
        }

#pragma unroll
        for (int i = 0; i < 4; ++i)
#pragma unroll
            for (int r = 0; r < 4; ++r) {
                const int m = t * 128 + wm + i * 16 + quad * 4 + r;
#pragma unroll
                for (int j = 0; j < 4; ++j) {
                    const int n = n0 + wn + j * 16 + lr;
                    gi_wemb[(size_t)m * G3_ + n] = f2bf(acc[i][j][r]);
                }
            }
        return;
    }

    // ---- pfx: gi_img (bids 1..12) / h0 (bids 13..16), K = 2048 ----
    const int px = bid - SU_PFX0;
    const bool isH0 = px >= 12;
    const float* Bm = isH0 ? init_w : W_ih;
    const int ldb = isH0 ? IC_ : D_;
    const int n0 = isH0 ? (px - 12) * 128 : px * 128;
    const float* bias = isH0 ? init_b : b_ih;

    const int ar0 = s_ord[srow];
    const int ar1 = s_ord[srow + 64];
    const int br0 = n0 + srow, br1 = n0 + srow + 64;

    uint4 a0 = load_cvt<true>(image_code, (size_t)ar0 * IC_ + ch * 8);
    uint4 a1 = load_cvt<true>(image_code, (size_t)ar1 * IC_ + ch * 8);
    uint4 b0 = load_cvt<true>(Bm, (size_t)br0 * ldb + ch * 8);
    uint4 b1 = load_cvt<true>(Bm, (size_t)br1 * ldb + ch * 8);

    for (int k0 = 0; k0 < IC_; k0 += 32) {
        __syncthreads();
        *(uint4*)&As[(srow)      * 32 + ch * 8] = a0;
        *(uint4*)&As[(srow + 64) * 32 + ch * 8] = a1;
        *(uint4*)&Bs[(srow)      * 32 + ch * 8] = b0;
        *(uint4*)&Bs[(srow + 64) * 32 + ch * 8] = b1;
        __syncthreads();
        short8 af[4], bfr[4];
#pragma unroll
        for (int i = 0; i < 4; ++i) af[i]  = *(const short8*)&As[(wm + i * 16 + lr) * 32 + quad * 8];
#pragma unroll
        for (int j = 0; j < 4; ++j) bfr[j] = *(const short8*)&Bs[(wn + j * 16 + lr) * 32 + quad * 8];
        if (k0 + 32 < IC_) {
            a0 = load_cvt<true>(image_code, (size_t)ar0 * IC_ + k0 + 32 + ch * 8);
            a1 = load_cvt<true>(image_code, (size_t)ar1 * IC_ + k0 + 32 + ch * 8);
            b0 = load_cvt<true>(Bm, (size_t)br0 * ldb + k0 + 32 + ch * 8);
            b1 = load_cvt<true>(Bm, (size_t)br1 * ldb + k0 + 32 + ch * 8);
        }
#pragma unroll
        for (int i = 0; i < 4; ++i)
#pragma unroll
            for (int j = 0; j < 4; ++j) acc[i][j] = mfma16(af[i], bfr[j], acc[i][j]);
    }

#pragma unroll
    for (int i = 0; i < 4; ++i)
#pragma unroll
        for (int r = 0; r < 4; ++r) {
            const int m = wm + i * 16 + quad * 4 + r;
#pragma unroll
            for (int j = 0; j < 4; ++j) {
                const int n = n0 + wn + j * 16 + lr;
                const float v = acc[i][j][r] + bias[n];
                if (isH0) outs[(size_t)m * H_ + n] = f2bf(v);
                else      gi_img[(size_t)m * G3_ + n] = v;
            }
        }
}

// ---------------------------------------------------------------------------
// FUSED recurrence + output projection — exact R5 structure (proven 184 µs),
// with ONE register-level change: gi loads hit the PURE gi_wemb; gi_img
// (constant per thread across steps, 12 f32) and b_hh r/z biases are
// preloaded once and added in the gate math. No gating, no work pool.
// 86 KB LDS -> 1 block/CU; grid 222 <= 256 CUs, all resident.
// ---------------------------------------------------------------------------
#define PBS_STR 520
__global__ __launch_bounds__(256, 1) void k_fused(
    const ushort_t* __restrict__ whh_bf,   // (32,48,512)
    const ushort_t* __restrict__ gi_wemb,  // (31*128,1536) pure emb part
    const float* __restrict__ b_hh,        // (1536)
    ushort_t* __restrict__ outs,           // (32,128,512)
    const ushort_t* __restrict__ fcw_bf,   // (10112,512)
    const float* __restrict__ fc_b,        // (10000)
    const int* __restrict__ len_i,         // (128)
    float* __restrict__ out,               // (128,31,10000)
    int* __restrict__ sync,                // distributed flags (fcw pad rows)
    const float* __restrict__ gi_img)      // (128,1536) f32
{
    __shared__ __align__(16) ushort_t sm[43008];   // 86,016 B -> 1 block/CU
    const int bid = blockIdx.x;
    const int tid = threadIdx.x;
    const int w = tid >> 6, lane = tid & 63, quad = lane >> 4, lr = lane & 15;

    if (bid < NPROD_) {
        // ---------------- producer (solo CU) ----------------
        __builtin_amdgcn_s_setprio(1);
        const int g = bid & 31;
        const int ih = bid >> 5;
        const bool leader = (bid == (ih << 5));   // bid 0 and 32
        ushort_t* Bs = sm;                 // 48 x 520

        const ushort_t* wsrc = whh_bf + (size_t)g * 48 * 512;
        for (int i = tid; i < 48 * 64; i += 256) {
            const int row = i >> 6, c = i & 63;
            *(uint4*)&Bs[row * PBS_STR + c * 8] = *(const uint4*)&wsrc[row * 512 + c * 8];
        }
        const int cg = g * 16 + lr;        // gh col
        const float bhr = b_hh[cg];
        const float bhz = b_hh[512 + cg];
        const float bhn = b_hh[1024 + cg];
        __syncthreads();

        // constants per thread: gi_img (step-invariant) + h0
        float gim0[4], gim1[4], gim2[4];
        float hold_reg[4];
        {
            const ushort_t* h0p = outs + (size_t)ih * 64 * 512;
#pragma unroll
            for (int r = 0; r < 4; ++r) {
                const int b = ih * 64 + w * 16 + quad * 4 + r;
                const float* pim = gi_img + (size_t)b * G3_ + cg;
                gim0[r] = pim[0]; gim1[r] = pim[512]; gim2[r] = pim[1024];
                hold_reg[r] = bf2f(h0p[(size_t)(w * 16 + quad * 4 + r) * 512 + cg]);
            }
        }
        // gi prefetch for step 0
        ushort_t gi0[4], gi1[4], gi2[4];
#pragma unroll
        for (int r = 0; r < 4; ++r) {
            const int b = ih * 64 + w * 16 + quad * 4 + r;
            const ushort_t* p = gi_wemb + (size_t)b * G3_ + cg;
            gi0[r] = p[0]; gi1[r] = p[512]; gi2[r] = p[1024];
        }

        for (int step = 0; step < T_; ++step) {
            const ushort_t* hsrc = outs + (size_t)step * (128 * 512) + (size_t)ih * 64 * 512;

            // h_t A-fragments: per-lane contiguous 16B chunks straight to regs
            uint4 hv[16];
            const ushort_t* hrow = hsrc + (size_t)(w * 16 + lr) * 512 + quad * 8;
#pragma unroll
            for (int kk = 0; kk < 16; ++kk)
                hv[kk] = *(const uint4*)(hrow + kk * 32);

            f32x4 acc[3];
#pragma unroll
            for (int j = 0; j < 3; ++j) acc[j] = (f32x4){0.f, 0.f, 0.f, 0.f};
#pragma unroll
            for (int kk = 0; kk < 16; ++kk) {
                union { uint4 v; short8 s; } cc; cc.v = hv[kk];
                const short8 af = cc.s;
#pragma unroll
                for (int j = 0; j < 3; ++j) {
                    const short8 bf = *(const short8*)&Bs[(j * 16 + lr) * PBS_STR + kk * 32 + quad * 8];
                    acc[j] = mfma16(af, bf, acc[j]);
                }
            }

            // gates (C-layout: col=lr, row=quad*4+r)
            ushort_t* hdst = outs + (size_t)(step + 1) * (128 * 512);
#pragma unroll
            for (int r = 0; r < 4; ++r) {
                const int b = ih * 64 + w * 16 + quad * 4 + r;
                const float ir  = bf2f(gi0[r]) + gim0[r] + bhr;
                const float iz  = bf2f(gi1[r]) + gim1[r] + bhz;
                const float in_ = bf2f(gi2[r]) + gim2[r];
                const float hr = acc[0][r];
                const float hz = acc[1][r];
                const float hn = acc[2][r] + bhn;
                const float rg = 1.f / (1.f + __expf(-(ir + hr)));
                const float zg = 1.f / (1.f + __expf(-(iz + hz)));
                const float nn = tanhf(in_ + rg * hn);
                const float hnew = (1.f - zg) * nn + zg * hold_reg[r];
                const unsigned int hb = (unsigned int)f2bf(hnew);
                hold_reg[r] = bf2f((unsigned short)hb);   // bit-compat carry
                const unsigned int pv = (unsigned int)__shfl_xor((int)hb, 1);
                if ((lr & 1) == 0) {
                    const unsigned int word = hb | (pv << 16);
                    __hip_atomic_store((unsigned int*)&hdst[(size_t)b * 512 + cg], word,
                                       __ATOMIC_RELAXED, __HIP_MEMORY_SCOPE_AGENT);
                }
            }

            // release: drain write-through stores, then distributed signal
            asm volatile("s_waitcnt vmcnt(0)" ::: "memory");
            __syncthreads();
            const int tgt = step + 1;
            if (tid == 0)
                __hip_atomic_store(&sync[bid * 8], tgt,
                                   __ATOMIC_RELAXED, __HIP_MEMORY_SCOPE_AGENT);

            // prefetch next step's gi (independent of h) under the wait
            ushort_t ng0[4], ng1[4], ng2[4];
            if (step + 1 < T_) {
                const size_t gb = (size_t)(step + 1) * 128 * G3_;
#pragma unroll
                for (int r = 0; r < 4; ++r) {
                    const int b = ih * 64 + w * 16 + quad * 4 + r;
                    const ushort_t* p = gi_wemb + gb + (size_t)b * G3_ + cg;
                    ng0[r] = p[0]; ng1[r] = p[512]; ng2[r] = p[1024];
                }
            }
            asm volatile("" ::: "memory");

            // wave 0 only polls the 32 same-half flags, with backoff
            if (w == 0 && (step < T_ - 1 || leader)) {
                const int* pf = &sync[(ih * 32 + (lane & 31)) * 8];
                for (;;) {
                    const int v = __hip_atomic_load(pf, __ATOMIC_RELAXED, __HIP_MEMORY_SCOPE_AGENT);
                    if (__all(v >= tgt)) break;
                    __builtin_amdgcn_s_sleep(1);
                }
                if (leader && lane == 0) {
#pragma unroll
                    for (int k = 0; k < 8; ++k)
                        __hip_atomic_store(&sync[768 + k * 16 + ih], tgt,
                                           __ATOMIC_RELAXED, __HIP_MEMORY_SCOPE_AGENT);
                }
            }
            __syncthreads();          // release waves 1-3
            asm volatile("" ::: "memory");

            if (step + 1 < T_) {
#pragma unroll
                for (int r = 0; r < 4; ++r) { gi0[r] = ng0[r]; gi1[r] = ng1[r]; gi2[r] = ng2[r]; }
            }
        }
    } else {
        // ---------------- nb-affine consumer (solo CU) -- exact R5 ----------
        const int cid = bid - NPROD_;          // [0, 158)
        const int nb = cid % 79;               // FIXED fcw slab per block
        const int team = cid / 79;             // {0, 1}
        const int n0 = nb * 128;
        ushort_t* As = sm;            // 128 x 32
        ushort_t* Bs = sm + 4096;     // 128 x 32
        const int srow = tid >> 2, ch = tid & 3;
        const int wm = (w & 1) * 64, wn = (w >> 1) * 64;
        const ull_t* hready = (const ull_t*)&sync[768 + (cid & 7) * 16];

        float fcb[4];
#pragma unroll
        for (int j = 0; j < 4; ++j) {
            const int n = n0 + wn + j * 16 + lr;
            fcb[j] = (n < V_) ? fc_b[n] : 0.f;
        }

        for (int t = team; t < T_; t += NTEAM_) {
            if (tid == 0) {
                for (;;) {
                    const ull_t hv8 = __hip_atomic_load(hready, __ATOMIC_RELAXED, __HIP_MEMORY_SCOPE_AGENT);
                    const int l0 = (int)(unsigned int)(hv8 & 0xffffffffull);
                    const int l1 = (int)(unsigned int)(hv8 >> 32);
                    if (l0 > t && l1 > t) break;
                    __builtin_amdgcn_s_sleep(16);
                }
            }
            __syncthreads();

            const ushort_t* A = outs + (size_t)(t + 1) * (128 * 512);

            f32x4 acc[4][4];
            const f32x4 z4 = {0.f, 0.f, 0.f, 0.f};
#pragma unroll
            for (int i = 0; i < 4; ++i)
#pragma unroll
                for (int j = 0; j < 4; ++j) acc[i][j] = z4;

            uint4 a0 = *(const uint4*)&A[(size_t)srow * 512 + ch * 8];
            uint4 a1 = *(const uint4*)&A[(size_t)(srow + 64) * 512 + ch * 8];
            uint4 b0 = *(const uint4*)&fcw_bf[(size_t)(n0 + srow)      * 512 + ch * 8];
            uint4 b1 = *(const uint4*)&fcw_bf[(size_t)(n0 + srow + 64) * 512 + ch * 8];

            for (int k0 = 0; k0 < 512; k0 += 32) {
                __syncthreads();
                *(uint4*)&As[(srow)      * 32 + ch * 8] = a0;
                *(uint4*)&As[(srow + 64) * 32 + ch * 8] = a1;
                *(uint4*)&Bs[(srow)      * 32 + ch * 8] = b0;
                *(uint4*)&Bs[(srow + 64) * 32 + ch * 8] = b1;
                __syncthreads();
                short8 af[4], bfr[4];
#pragma unroll
                for (int i = 0; i < 4; ++i) af[i]  = *(const short8*)&As[(wm + i * 16 + lr) * 32 + quad * 8];
#pragma unroll
                for (int j = 0; j < 4; ++j) bfr[j] = *(const short8*)&Bs[(wn + j * 16 + lr) * 32 + quad * 8];
                if (k0 + 32 < 512) {
                    a0 = *(const uint4*)&A[(size_t)srow * 512 + k0 + 32 + ch * 8];
                    a1 = *(const uint4*)&A[(size_t)(srow + 64) * 512 + k0 + 32 + ch * 8];
                    b0 = *(const uint4*)&fcw_bf[(size_t)(n0 + srow)      * 512 + k0 + 32 + ch * 8];
                    b1 = *(const uint4*)&fcw_bf[(size_t)(n0 + srow + 64) * 512 + k0 + 32 + ch * 8];
                }
#pragma unroll
                for (int i = 0; i < 4; ++i)
#pragma unroll
                    for (int j = 0; j < 4; ++j) acc[i][j] = mfma16(af[i], bfr[j], acc[i][j]);
            }

#pragma unroll
            for (int i = 0; i < 4; ++i)
#pragma unroll
                for (int r = 0; r < 4; ++r) {
                    const int b = wm + i * 16 + quad * 4 + r;
                    const bool act = (t < len_i[b]);
                    const size_t base = (size_t)b * T_ * V_ + (size_t)t * V_;
#pragma unroll
                    for (int j = 0; j < 4; ++j) {
                        const int n = n0 + wn + j * 16 + lr;
                        if (n < V_) out[base + n] = act ? (acc[i][j][r] + fcb[j]) : 0.f;
                    }
                }
        }
    }
}

// ---------------------------------------------------------------------------
extern "C" void kernel_launch(void* const* d_in, const int* in_sizes, int n_in,
                              void* d_out, int out_size, void* d_ws, size_t ws_size,
                              hipStream_t stream) {
    const float* image_code = (const float*)d_in[0];
    const int*   captions   = (const int*)d_in[1];
    const int*   cap_lens   = (const int*)d_in[2];
    const float* embed_w    = (const float*)d_in[3];
    const float* W_ih       = (const float*)d_in[4];
    const float* W_hh       = (const float*)d_in[5];
    const float* b_ih       = (const float*)d_in[6];
    const float* b_hh       = (const float*)d_in[7];
    const float* fc_w       = (const float*)d_in[8];
    const float* fc_b       = (const float*)d_in[9];
    const float* init_w     = (const float*)d_in[10];
    const float* init_b     = (const float*)d_in[11];

    float* out = (float*)d_out;
    char* ws = (char*)d_ws;
    int*      order   = (int*)(ws + WS_ORDER);
    int*      len_i   = (int*)(ws + WS_LEN);
    int*      bar     = (int*)(ws + WS_BAR);
    float*    gi_img  = (float*)(ws + WS_GIIMG);
    ushort_t* whh_bf  = (ushort_t*)(ws + WS_WHH);
    ushort_t* gi_wemb = (ushort_t*)(ws + WS_GIWEMB);
    ushort_t* outs_bf = (ushort_t*)(ws + WS_OUTS);
    ushort_t* fcw_bf  = (ushort_t*)(ws + WS_FCW);
    int*      sync    = (int*)(fcw_bf + ((size_t)NPAD_ - 4) * 512);

    // 1) one setup launch: prep + pfx + gi_wemb gemm + both weight converts
    hipLaunchKernelGGL(k_setup, dim3(SU_N), dim3(256), 0, stream,
                       captions, cap_lens, fc_w, W_hh,
                       image_code, W_ih, b_ih, init_w, init_b, embed_w,
                       fcw_bf, whh_bf, gi_img, gi_wemb, outs_bf,
                       order, len_i, bar,
                       out + (size_t)B_ * T_ * V_);

    // 2) fused persistent recurrence + streaming output projection
    hipLaunchKernelGGL(k_fused, dim3(NPROD_ + NCONS_), dim3(256), 0, stream,
                       whh_bf, gi_wemb, b_hh, outs_bf,
                       fcw_bf, fc_b, len_i, out, sync, gi_img);
}